// Round 2
// baseline (37825.153 us; speedup 1.0000x reference)
//
#include <hip/hip_runtime.h>
#include <math.h>

// Sizes fixed by the problem
#define D_DIM 1024
#define S_LEN 2048
#define B_SZ  4
#define GRU_BLOCKS 64    // x 1024 threads (16 waves); wave owns one j

union F4 { float4 v; float f[4]; };

__device__ __forceinline__ float gelu_f(float x) {
  return 0.5f * x * (1.0f + erff(x * 0.70710678118654752440f));
}
__device__ __forceinline__ float sigmoid_f(float x) {
  return 1.0f / (1.0f + __expf(-x));
}

// ---------------- LayerNorm: one block per row of 1024 ----------------
__global__ __launch_bounds__(256) void ln_kernel(
    const float* __restrict__ x, const float* __restrict__ gamma,
    const float* __restrict__ beta, float* __restrict__ out) {
  const int row = blockIdx.x;
  const int tid = threadIdx.x;
  const int wave = tid >> 6, lane = tid & 63;
  const float4 v = ((const float4*)(x + (size_t)row * D_DIM))[tid];
  float s  = v.x + v.y + v.z + v.w;
  float ss = v.x * v.x + v.y * v.y + v.z * v.z + v.w * v.w;
#pragma unroll
  for (int m = 1; m < 64; m <<= 1) {
    s  += __shfl_xor(s,  m, 64);
    ss += __shfl_xor(ss, m, 64);
  }
  __shared__ float r0[4], r1[4];
  if (lane == 0) { r0[wave] = s; r1[wave] = ss; }
  __syncthreads();
  s  = r0[0] + r0[1] + r0[2] + r0[3];
  ss = r1[0] + r1[1] + r1[2] + r1[3];
  const float mean = s * (1.0f / D_DIM);
  const float var  = ss * (1.0f / D_DIM) - mean * mean;
  const float inv  = rsqrtf(var + 1e-5f);
  const float4 g4 = ((const float4*)gamma)[tid];
  const float4 b4 = ((const float4*)beta)[tid];
  float4 o;
  o.x = (v.x - mean) * inv * g4.x + b4.x;
  o.y = (v.y - mean) * inv * g4.y + b4.y;
  o.z = (v.z - mean) * inv * g4.z + b4.z;
  o.w = (v.w - mean) * inv * g4.w + b4.w;
  ((float4*)(out + (size_t)row * D_DIM))[tid] = o;
}

// ---------------- Generic SGEMM: C = A @ W^T (+bias)(+act)(+res) ----------------
// A: (M,K) lda, W: (N,K) ldw, C: (M,N) dense. act: 0=none, 1=gelu.
#define BM 128
#define BN 128
#define BKK 8
#define TM 8
#define TN 8
__global__ __launch_bounds__(256) void gemm_kernel(
    const float* __restrict__ A, int lda,
    const float* __restrict__ W, int ldw,
    const float* __restrict__ bias,
    const float* __restrict__ res,
    float* __restrict__ C,
    int M, int N, int K, int act) {
  __shared__ float As[BKK][BM];
  __shared__ float Bs[BKK][BN];
  const int tid = threadIdx.x;
  const int bm = blockIdx.y * BM;
  const int bn = blockIdx.x * BN;
  const int tx = tid & 15;
  const int ty = tid >> 4;
  const int lrow = tid >> 1;
  const int lk = (tid & 1) * 4;
  const float* Ag = A + (size_t)(bm + lrow) * lda + lk;
  const float* Wg = W + (size_t)(bn + lrow) * ldw + lk;

  float acc[TM][TN];
#pragma unroll
  for (int i = 0; i < TM; ++i)
#pragma unroll
    for (int j = 0; j < TN; ++j) acc[i][j] = 0.0f;

  for (int k0 = 0; k0 < K; k0 += BKK) {
    const float4 av = *(const float4*)(Ag + k0);
    const float4 wv = *(const float4*)(Wg + k0);
    __syncthreads();
    As[lk + 0][lrow] = av.x; As[lk + 1][lrow] = av.y;
    As[lk + 2][lrow] = av.z; As[lk + 3][lrow] = av.w;
    Bs[lk + 0][lrow] = wv.x; Bs[lk + 1][lrow] = wv.y;
    Bs[lk + 2][lrow] = wv.z; Bs[lk + 3][lrow] = wv.w;
    __syncthreads();
#pragma unroll
    for (int k = 0; k < BKK; ++k) {
      F4 a0, a1, b0, b1;
      a0.v = *(const float4*)(&As[k][ty * TM]);
      a1.v = *(const float4*)(&As[k][ty * TM + 4]);
      b0.v = *(const float4*)(&Bs[k][tx * TN]);
      b1.v = *(const float4*)(&Bs[k][tx * TN + 4]);
      float a[TM] = {a0.f[0], a0.f[1], a0.f[2], a0.f[3],
                     a1.f[0], a1.f[1], a1.f[2], a1.f[3]};
      float b[TN] = {b0.f[0], b0.f[1], b0.f[2], b0.f[3],
                     b1.f[0], b1.f[1], b1.f[2], b1.f[3]};
#pragma unroll
      for (int i = 0; i < TM; ++i)
#pragma unroll
        for (int j = 0; j < TN; ++j) acc[i][j] += a[i] * b[j];
    }
  }

  float bs_[TN];
#pragma unroll
  for (int j = 0; j < TN; ++j) bs_[j] = bias ? bias[bn + tx * TN + j] : 0.0f;
#pragma unroll
  for (int i = 0; i < TM; ++i) {
    const size_t coff = (size_t)(bm + ty * TM + i) * N + bn + tx * TN;
    float vals[TN];
#pragma unroll
    for (int j = 0; j < TN; ++j) {
      float v = acc[i][j] + bs_[j];
      if (act == 1) v = gelu_f(v);
      vals[j] = v;
    }
    if (res) {
#pragma unroll
      for (int j = 0; j < TN; ++j) vals[j] += res[coff + j];
    }
    *(float4*)(C + coff)     = make_float4(vals[0], vals[1], vals[2], vals[3]);
    *(float4*)(C + coff + 4) = make_float4(vals[4], vals[5], vals[6], vals[7]);
  }
}

// ---------------- Persistent GRU layer ----------------
// 64 blocks x 1024 threads (16 waves). Wave w of block bid owns j = bid*16+w.
// h_{t-1} staged once per block into LDS via coherent global_load_dwordx4
// (sc0 sc1 = bypass L1/per-XCD L2, read coherence point). k-ownership per
// lane: k = c*256 + lane*4 + e (contiguous ds_read_b128, conflict-free).
// Round-6 changes vs round-5 (protocol ordering UNCHANGED):
//  (a) device barrier: central atomic fetch_add (128 serialized RMWs at one
//      LLC line, ~4k cy) -> per-block slot stores (64B-strided, parallel) +
//      wave-0 gather poll with __all(slot >= t+1). Slot store still issued
//      only AFTER __syncthreads drained vmcnt(0), so slot=t+1 => that
//      block's h-stores are at the coherence point. Pollers relaxed loads.
//  (b) xi double-buffered in registers: step t+1's 12 loads issued right
//      after the LDS-stage sync, consumed next iteration (HBM latency
//      hidden under compute + barrier, out of the h-load vmcnt window).
//  (c) 64x1024 instead of 128x512: half the arrivals/staging, 1 slot/lane.
// NO threadfence / NO acquire anywhere (round-1 lesson: wbl2/inv storm).
// Ping-pong h buffers make WAR safe: block arrives at barrier t only after
// its reads of buf[t&1] are done; step t+1 writes buf[t&1] only after all
// slots >= t+1.
__global__ __launch_bounds__(1024, 1) void gru_kernel(
    const float* __restrict__ xi,    // (B,S,3H)
    const float* __restrict__ Whh,   // (3H,H)
    const float* __restrict__ bhh,   // (3H)
    const float* __restrict__ resid, // nullptr or (B,S,H)
    float* __restrict__ y,           // (B,S,H)
    float* __restrict__ hbuf,        // 2*4096 floats, zero-initialized
    unsigned* __restrict__ slots)    // GRU_BLOCKS slots, 16-u32 stride, zeroed
{
  const int tid = threadIdx.x;
  const int wave = tid >> 6, lane = tid & 63;
  const int j = (blockIdx.x << 4) + wave;  // 0..1023

  __shared__ float h_lds[4 * 1024];  // 16KB: h_{t-1} for all 4 batches

  // weights: w[g][c][e] = Whh[g*1024+j][c*256 + lane*4 + e]  (coalesced f4)
  float w[3][4][4];
#pragma unroll
  for (int g = 0; g < 3; ++g) {
    const float* row = Whh + (size_t)(g * 1024 + j) * 1024;
#pragma unroll
    for (int c = 0; c < 4; ++c) {
      F4 q; q.v = *(const float4*)(row + (c << 8) + (lane << 2));
#pragma unroll
      for (int e = 0; e < 4; ++e) w[g][c][e] = q.f[e];
    }
  }
  const float bh0 = bhh[j], bh1 = bhh[1024 + j], bh2 = bhh[2048 + j];

  // h_prev at this wave's own j: register-resident, identical in all lanes.
  float hold[B_SZ] = {0.0f, 0.0f, 0.0f, 0.0f};

  // xi prologue (t = 0); cached loads, wave-uniform address (broadcast)
  float xr[B_SZ], xz[B_SZ], xn[B_SZ];
#pragma unroll
  for (int b = 0; b < B_SZ; ++b) {
    const float* xp = xi + ((size_t)(b * S_LEN)) * 3072 + j;
    xr[b] = xp[0]; xz[b] = xp[1024]; xn[b] = xp[2048];
  }

  for (int t = 0; t < S_LEN; ++t) {
    float* hr_ = hbuf + ((t & 1) << 12);
    float* hw_ = hbuf + (((t + 1) & 1) << 12);

    // Stage h_{t-1} (4 x 1024 floats) into LDS: each of 1024 threads loads
    // one coherent dwordx4 (sc0 sc1 -> serviced at the coherence point).
    {
      const float* p = hr_ + (tid << 2);
      float4 r0;
      asm volatile("global_load_dwordx4 %0, %1, off sc0 sc1"
                   : "=v"(r0) : "v"(p));
      asm volatile("s_waitcnt vmcnt(0)" ::: "memory");
      __builtin_amdgcn_sched_barrier(0);
      ((float4*)h_lds)[tid] = r0;
    }
    __syncthreads();

    // Issue next step's xi loads now; latency hides under compute + barrier.
    float nxr[B_SZ], nxz[B_SZ], nxn[B_SZ];
    {
      const int tn = (t + 1 < S_LEN) ? (t + 1) : (S_LEN - 1);
#pragma unroll
      for (int b = 0; b < B_SZ; ++b) {
        const float* xp = xi + ((size_t)(b * S_LEN + tn)) * 3072 + j;
        nxr[b] = xp[0]; nxz[b] = xp[1024]; nxn[b] = xp[2048];
      }
    }

    // LDS -> regs: h[b][c][e] = h_lds[b*1024 + c*256 + lane*4 + e]
    float h[B_SZ][4][4];
#pragma unroll
    for (int b = 0; b < B_SZ; ++b)
#pragma unroll
      for (int c = 0; c < 4; ++c) {
        F4 q; q.v = *((const float4*)(h_lds + (b << 10) + (c << 8)) + lane);
#pragma unroll
        for (int e = 0; e < 4; ++e) h[b][c][e] = q.f[e];
      }

    // partial dots over this lane's 16 k's
    float a0[B_SZ], a1[B_SZ], a2[B_SZ];
#pragma unroll
    for (int b = 0; b < B_SZ; ++b) {
      float s0 = 0.f, s1 = 0.f, s2 = 0.f;
#pragma unroll
      for (int c = 0; c < 4; ++c)
#pragma unroll
        for (int e = 0; e < 4; ++e) {
          s0 += w[0][c][e] * h[b][c][e];
          s1 += w[1][c][e] * h[b][c][e];
          s2 += w[2][c][e] * h[b][c][e];
        }
      a0[b] = s0; a1[b] = s1; a2[b] = s2;
    }
    // butterfly reduce across 64 lanes (result in every lane)
#pragma unroll
    for (int m = 1; m < 64; m <<= 1)
#pragma unroll
      for (int b = 0; b < B_SZ; ++b) {
        a0[b] += __shfl_xor(a0[b], m, 64);
        a1[b] += __shfl_xor(a1[b], m, 64);
        a2[b] += __shfl_xor(a2[b], m, 64);
      }

    // gates (redundant in all lanes)
    float hnew[B_SZ];
#pragma unroll
    for (int b = 0; b < B_SZ; ++b) {
      const float r = sigmoid_f(xr[b] + a0[b] + bh0);
      const float z = sigmoid_f(xz[b] + a1[b] + bh1);
      const float n = tanhf(xn[b] + r * (a2[b] + bh2));
      hnew[b] = (1.0f - z) * n + z * hold[b];
      hold[b] = hnew[b];
    }

    // lane b (0..3) stores batch b's value for this j
    float sv = hnew[0];
    sv = (lane == 1) ? hnew[1] : sv;
    sv = (lane == 2) ? hnew[2] : sv;
    sv = (lane == 3) ? hnew[3] : sv;
    if (lane < B_SZ) {
      __hip_atomic_store(hw_ + (lane << 10) + j, sv,
                         __ATOMIC_RELAXED, __HIP_MEMORY_SCOPE_AGENT);
      const size_t oidx = ((size_t)(lane * S_LEN + t)) * 1024 + j;
      y[oidx] = resid ? (sv + resid[oidx]) : sv;
    }

    // ---- device-wide barrier: slot stores + gather poll ----
    __syncthreads();  // drains vmcnt(0): all waves' sc1 h-stores complete
    if (tid == 0)
      __hip_atomic_store(slots + (blockIdx.x << 4), (unsigned)(t + 1),
                         __ATOMIC_RELAXED, __HIP_MEMORY_SCOPE_AGENT);
    if (wave == 0) {
      const unsigned target = (unsigned)(t + 1);
      for (;;) {
        const unsigned v = __hip_atomic_load(slots + (lane << 4),
                                             __ATOMIC_RELAXED,
                                             __HIP_MEMORY_SCOPE_AGENT);
        if (__all(v >= target)) break;
        __builtin_amdgcn_s_sleep(1);
      }
    }
    __syncthreads();

    // rotate xi double-buffer
#pragma unroll
    for (int b = 0; b < B_SZ; ++b) {
      xr[b] = nxr[b]; xz[b] = nxz[b]; xn[b] = nxn[b];
    }
  }
}

// ---------------- column mean over S (gc = mean_t h2[b,t,:]) ----------------
__global__ __launch_bounds__(256) void colmean_kernel(
    const float* __restrict__ in, float* __restrict__ gc) {
  const int b = blockIdx.x >> 3, tc = blockIdx.x & 7;
  const int d = threadIdx.x;
  float s0 = 0.f, s1 = 0.f, s2 = 0.f, s3 = 0.f;
  const float* base = in + ((size_t)b * S_LEN + tc * 256) * D_DIM;
  for (int t = 0; t < 256; ++t) {
    const float* r = base + (size_t)t * D_DIM;
    s0 += r[d]; s1 += r[d + 256]; s2 += r[d + 512]; s3 += r[d + 768];
  }
  const float sc = 1.0f / (float)S_LEN;
  atomicAdd(&gc[b * D_DIM + d], s0 * sc);
  atomicAdd(&gc[b * D_DIM + d + 256], s1 * sc);
  atomicAdd(&gc[b * D_DIM + d + 512], s2 * sc);
  atomicAdd(&gc[b * D_DIM + d + 768], s3 * sc);
}

// ---------------- global MLP: gc(b,1024)->512->256->1, sigmoid ----------------
__global__ __launch_bounds__(256) void gmlp_kernel(
    const float* __restrict__ gc,
    const float* __restrict__ gw1, const float* __restrict__ gb1,
    const float* __restrict__ gw2, const float* __restrict__ gb2,
    const float* __restrict__ gw3, const float* __restrict__ gb3,
    float* __restrict__ gout) {
  const int b = blockIdx.x, tid = threadIdx.x;
  __shared__ float xin[1024];
  __shared__ float h1[512];
  __shared__ float h2[256];
#pragma unroll
  for (int i = 0; i < 4; ++i) xin[tid + i * 256] = gc[b * 1024 + tid + i * 256];
  __syncthreads();
  for (int o = tid; o < 512; o += 256) {
    const float* wr = gw1 + (size_t)o * 1024;
    float acc = gb1[o];
    for (int k = 0; k < 1024; k += 4) {
      const float4 wv = *(const float4*)(wr + k);
      acc += wv.x * xin[k] + wv.y * xin[k + 1] + wv.z * xin[k + 2] + wv.w * xin[k + 3];
    }
    h1[o] = gelu_f(acc);
  }
  __syncthreads();
  {
    const float* wr = gw2 + (size_t)tid * 512;
    float acc = gb2[tid];
    for (int k = 0; k < 512; k += 4) {
      const float4 wv = *(const float4*)(wr + k);
      acc += wv.x * h1[k] + wv.y * h1[k + 1] + wv.z * h1[k + 2] + wv.w * h1[k + 3];
    }
    h2[tid] = gelu_f(acc);
  }
  __syncthreads();
  float p = h2[tid] * gw3[tid];
#pragma unroll
  for (int m = 1; m < 64; m <<= 1) p += __shfl_xor(p, m, 64);
  __shared__ float rr[4];
  if ((tid & 63) == 0) rr[tid >> 6] = p;
  __syncthreads();
  if (tid == 0) gout[b] = sigmoid_f(rr[0] + rr[1] + rr[2] + rr[3] + gb3[0]);
}

// ---------------- coupling MLP final layer: (8192,256)@(256,) -> sigmoid ----------------
__global__ __launch_bounds__(256) void gemv_sig_kernel(
    const float* __restrict__ A, const float* __restrict__ w,
    const float* __restrict__ bias, float* __restrict__ out) {
  const int row = blockIdx.x * 4 + (threadIdx.x >> 6);
  const int lane = threadIdx.x & 63;
  F4 a, wv;
  a.v  = ((const float4*)(A + (size_t)row * 256))[lane];
  wv.v = ((const float4*)w)[lane];
  float p = a.f[0] * wv.f[0] + a.f[1] * wv.f[1] + a.f[2] * wv.f[2] + a.f[3] * wv.f[3];
#pragma unroll
  for (int m = 1; m < 64; m <<= 1) p += __shfl_xor(p, m, 64);
  if (lane == 0) out[row] = sigmoid_f(p + bias[0]);
}

// ---------------- mobius coupling update (in place, conjugate pairs) ----------------
// quarters [a,b,c,d] -> out += coup*[c,-d,-a,b]; pair (d, d+512), sign flips at d=256.
__global__ __launch_bounds__(256) void mobius_kernel(
    float* __restrict__ out, const float* __restrict__ tf,
    const float* __restrict__ g, const float* __restrict__ ar,
    const float* __restrict__ res) {
  const int idx = blockIdx.x * 256 + threadIdx.x;   // over 8192*512
  const int row = idx >> 9;
  const int d = idx & 511;
  const int b = row >> 11;
  const float combined = 0.7f * g[b] + 0.3f * tf[row];
  const float coup = 0.1f + ar[0] * (combined - 0.5f) * 2.0f;
  float* base = out + (size_t)row * 1024;
  const float f = base[d], s2 = base[d + 512];
  const float sgn = (d < 256) ? 1.0f : -1.0f;
  float nf = f + sgn * coup * s2;
  float ns = s2 - sgn * coup * f;
  if (res) {
    const float* rb = res + (size_t)row * 1024;
    nf += rb[d];
    ns += rb[d + 512];
  }
  base[d] = nf;
  base[d + 512] = ns;
}

extern "C" void kernel_launch(void* const* d_in, const int* in_sizes, int n_in,
                              void* d_out, int out_size, void* d_ws, size_t ws_size,
                              hipStream_t stream) {
  (void)in_sizes; (void)n_in; (void)out_size; (void)ws_size;
  const float* x    = (const float*)d_in[0];
  const float* g1w  = (const float*)d_in[1];
  const float* g1b  = (const float*)d_in[2];
  const float* g2w  = (const float*)d_in[3];
  const float* g2b  = (const float*)d_in[4];
  const float* Wih0 = (const float*)d_in[5];
  const float* Whh0 = (const float*)d_in[6];
  const float* bih0 = (const float*)d_in[7];
  const float* bhh0 = (const float*)d_in[8];
  const float* Wih1 = (const float*)d_in[9];
  const float* Whh1 = (const float*)d_in[10];
  const float* bih1 = (const float*)d_in[11];
  const float* bhh1 = (const float*)d_in[12];
  const float* cw1 = (const float*)d_in[13]; const float* cb1 = (const float*)d_in[14];
  const float* cw2 = (const float*)d_in[15]; const float* cb2 = (const float*)d_in[16];
  const float* cw3 = (const float*)d_in[17]; const float* cb3 = (const float*)d_in[18];
  const float* cw4 = (const float*)d_in[19]; const float* cb4 = (const float*)d_in[20];
  const float* gw1 = (const float*)d_in[21]; const float* gb1 = (const float*)d_in[22];
  const float* gw2 = (const float*)d_in[23]; const float* gb2 = (const float*)d_in[24];
  const float* gw3 = (const float*)d_in[25]; const float* gb3 = (const float*)d_in[26];
  const float* ar  = (const float*)d_in[27];
  const float* fw1 = (const float*)d_in[28]; const float* fb1 = (const float*)d_in[29];
  const float* fw2 = (const float*)d_in[30]; const float* fb2 = (const float*)d_in[31];
  float* outp = (float*)d_out;

  // workspace layout (floats): A 25165824 | Bb 8388608 | small ~30792
  float* A  = (float*)d_ws;
  float* Bb = A + 25165824;
  float* small = Bb + 8388608;
  float* gc   = small;                 // 4096
  float* gbuf = small + 4096;          // 8
  float* tf   = small + 4104;          // 8192
  float* hb0  = small + 12296;         // 8192 (2x4096 ping-pong)
  float* hb1  = small + 20488;         // 8192
  unsigned* slots0 = (unsigned*)(small + 28680);  // 64 slots x 16 u32 stride
  unsigned* slots1 = (unsigned*)(small + 29704);  // 64 slots x 16 u32 stride
  hipMemsetAsync(small, 0, (size_t)(30728 + 64) * sizeof(float), stream);

  // Block 1: LN -> GRU0 -> GRU1 (+x residual fused into GRU1 store)
  ln_kernel<<<8192, 256, 0, stream>>>(x, g1w, g1b, Bb);
  gemm_kernel<<<dim3(24, 64), 256, 0, stream>>>(Bb, 1024, Wih0, 1024, bih0, nullptr,
                                                A, 8192, 3072, 1024, 0);
  gru_kernel<<<GRU_BLOCKS, 1024, 0, stream>>>(A, Whh0, bhh0, nullptr, Bb, hb0, slots0);
  gemm_kernel<<<dim3(24, 64), 256, 0, stream>>>(Bb, 1024, Wih1, 1024, bih1, nullptr,
                                                A, 8192, 3072, 1024, 0);
  gru_kernel<<<GRU_BLOCKS, 1024, 0, stream>>>(A, Whh1, bhh1, x, outp, hb1, slots1);

  // Block 2: LN -> adaptive mobius (3 cycles) ; x2 lives in outp
  ln_kernel<<<8192, 256, 0, stream>>>(outp, g2w, g2b, Bb);
  colmean_kernel<<<32, 256, 0, stream>>>(Bb, gc);
  gmlp_kernel<<<4, 256, 0, stream>>>(gc, gw1, gb1, gw2, gb2, gw3, gb3, gbuf);
  float* c1o = A;              // 8192x1024
  float* c2o = A + 12582912;   // 8192x512
  float* c3o = A + 20971520;   // 8192x256
  for (int cyc = 0; cyc < 3; ++cyc) {
    gemm_kernel<<<dim3(8, 64), 256, 0, stream>>>(Bb, 1024, cw1, 1024, cb1, nullptr,
                                                 c1o, 8192, 1024, 1024, 1);
    gemm_kernel<<<dim3(4, 64), 256, 0, stream>>>(c1o, 1024, cw2, 1024, cb2, nullptr,
                                                 c2o, 8192, 512, 1024, 1);
    gemm_kernel<<<dim3(2, 64), 256, 0, stream>>>(c2o, 512, cw3, 512, cb3, nullptr,
                                                 c3o, 8192, 256, 512, 1);
    gemv_sig_kernel<<<2048, 256, 0, stream>>>(c3o, cw4, cb4, tf);
    // final cycle fuses x3 = x2 + out
    mobius_kernel<<<16384, 256, 0, stream>>>(Bb, tf, gbuf, ar,
                                             (cyc == 2) ? outp : nullptr);
  }

  // Block 3: FFN residual, K chunked in 2 so hidden fits the A region
  for (int c = 0; c < 2; ++c) {
    gemm_kernel<<<dim3(16, 64), 256, 0, stream>>>(Bb, 1024,
        fw1 + (size_t)c * 2048 * 1024, 1024, fb1 + c * 2048, nullptr,
        A, 8192, 2048, 1024, 1);
    gemm_kernel<<<dim3(8, 64), 256, 0, stream>>>(A, 2048,
        fw2 + c * 2048, 4096, (c == 0) ? fb2 : nullptr,
        (c == 0) ? Bb : outp,
        outp, 8192, 1024, 2048, 0);
  }
}

// Round 3
// 20347.298 us; speedup vs baseline: 1.8590x; 1.8590x over previous
//
#include <hip/hip_runtime.h>
#include <math.h>

// Sizes fixed by the problem
#define D_DIM 1024
#define S_LEN 2048
#define B_SZ  4
#define GRU_BLOCKS 256   // x 256 threads (4 waves); wave owns one j; 1 block/CU

union F4 { float4 v; float f[4]; };

__device__ __forceinline__ float gelu_f(float x) {
  return 0.5f * x * (1.0f + erff(x * 0.70710678118654752440f));
}
__device__ __forceinline__ float sigmoid_f(float x) {
  return 1.0f / (1.0f + __expf(-x));
}

// ---------------- LayerNorm: one block per row of 1024 ----------------
__global__ __launch_bounds__(256) void ln_kernel(
    const float* __restrict__ x, const float* __restrict__ gamma,
    const float* __restrict__ beta, float* __restrict__ out) {
  const int row = blockIdx.x;
  const int tid = threadIdx.x;
  const int wave = tid >> 6, lane = tid & 63;
  const float4 v = ((const float4*)(x + (size_t)row * D_DIM))[tid];
  float s  = v.x + v.y + v.z + v.w;
  float ss = v.x * v.x + v.y * v.y + v.z * v.z + v.w * v.w;
#pragma unroll
  for (int m = 1; m < 64; m <<= 1) {
    s  += __shfl_xor(s,  m, 64);
    ss += __shfl_xor(ss, m, 64);
  }
  __shared__ float r0[4], r1[4];
  if (lane == 0) { r0[wave] = s; r1[wave] = ss; }
  __syncthreads();
  s  = r0[0] + r0[1] + r0[2] + r0[3];
  ss = r1[0] + r1[1] + r1[2] + r1[3];
  const float mean = s * (1.0f / D_DIM);
  const float var  = ss * (1.0f / D_DIM) - mean * mean;
  const float inv  = rsqrtf(var + 1e-5f);
  const float4 g4 = ((const float4*)gamma)[tid];
  const float4 b4 = ((const float4*)beta)[tid];
  float4 o;
  o.x = (v.x - mean) * inv * g4.x + b4.x;
  o.y = (v.y - mean) * inv * g4.y + b4.y;
  o.z = (v.z - mean) * inv * g4.z + b4.z;
  o.w = (v.w - mean) * inv * g4.w + b4.w;
  ((float4*)(out + (size_t)row * D_DIM))[tid] = o;
}

// ---------------- Generic SGEMM: C = A @ W^T (+bias)(+act)(+res) ----------------
// A: (M,K) lda, W: (N,K) ldw, C: (M,N) dense. act: 0=none, 1=gelu.
#define BM 128
#define BN 128
#define BKK 8
#define TM 8
#define TN 8
__global__ __launch_bounds__(256) void gemm_kernel(
    const float* __restrict__ A, int lda,
    const float* __restrict__ W, int ldw,
    const float* __restrict__ bias,
    const float* __restrict__ res,
    float* __restrict__ C,
    int M, int N, int K, int act) {
  __shared__ float As[BKK][BM];
  __shared__ float Bs[BKK][BN];
  const int tid = threadIdx.x;
  const int bm = blockIdx.y * BM;
  const int bn = blockIdx.x * BN;
  const int tx = tid & 15;
  const int ty = tid >> 4;
  const int lrow = tid >> 1;
  const int lk = (tid & 1) * 4;
  const float* Ag = A + (size_t)(bm + lrow) * lda + lk;
  const float* Wg = W + (size_t)(bn + lrow) * ldw + lk;

  float acc[TM][TN];
#pragma unroll
  for (int i = 0; i < TM; ++i)
#pragma unroll
    for (int j = 0; j < TN; ++j) acc[i][j] = 0.0f;

  for (int k0 = 0; k0 < K; k0 += BKK) {
    const float4 av = *(const float4*)(Ag + k0);
    const float4 wv = *(const float4*)(Wg + k0);
    __syncthreads();
    As[lk + 0][lrow] = av.x; As[lk + 1][lrow] = av.y;
    As[lk + 2][lrow] = av.z; As[lk + 3][lrow] = av.w;
    Bs[lk + 0][lrow] = wv.x; Bs[lk + 1][lrow] = wv.y;
    Bs[lk + 2][lrow] = wv.z; Bs[lk + 3][lrow] = wv.w;
    __syncthreads();
#pragma unroll
    for (int k = 0; k < BKK; ++k) {
      F4 a0, a1, b0, b1;
      a0.v = *(const float4*)(&As[k][ty * TM]);
      a1.v = *(const float4*)(&As[k][ty * TM + 4]);
      b0.v = *(const float4*)(&Bs[k][tx * TN]);
      b1.v = *(const float4*)(&Bs[k][tx * TN + 4]);
      float a[TM] = {a0.f[0], a0.f[1], a0.f[2], a0.f[3],
                     a1.f[0], a1.f[1], a1.f[2], a1.f[3]};
      float b[TN] = {b0.f[0], b0.f[1], b0.f[2], b0.f[3],
                     b1.f[0], b1.f[1], b1.f[2], b1.f[3]};
#pragma unroll
      for (int i = 0; i < TM; ++i)
#pragma unroll
        for (int j = 0; j < TN; ++j) acc[i][j] += a[i] * b[j];
    }
  }

  float bs_[TN];
#pragma unroll
  for (int j = 0; j < TN; ++j) bs_[j] = bias ? bias[bn + tx * TN + j] : 0.0f;
#pragma unroll
  for (int i = 0; i < TM; ++i) {
    const size_t coff = (size_t)(bm + ty * TM + i) * N + bn + tx * TN;
    float vals[TN];
#pragma unroll
    for (int j = 0; j < TN; ++j) {
      float v = acc[i][j] + bs_[j];
      if (act == 1) v = gelu_f(v);
      vals[j] = v;
    }
    if (res) {
#pragma unroll
      for (int j = 0; j < TN; ++j) vals[j] += res[coff + j];
    }
    *(float4*)(C + coff)     = make_float4(vals[0], vals[1], vals[2], vals[3]);
    *(float4*)(C + coff + 4) = make_float4(vals[4], vals[5], vals[6], vals[7]);
  }
}

// ---------------- Persistent GRU layer ----------------
// 256 blocks x 256 threads (4 waves). Wave w of block bid owns j = bid*4+w.
// GEOMETRY RATIONALE (round-3): all waves run in lockstep between device
// barriers, so per-step VALU issue time per CU = (waves/SIMD) x ~600 instr
// x 2cy. Measured: 16 waves/CU (R2) -> 3.6us/step VALU; 8 waves/CU (R1) ->
// 1.7us. This config: 4 waves/CU = 1/SIMD -> ~0.5us. Staging redundancy
// rises to 256 blocks x 16KB = 4MB/step from LLC (64K dwordx4 reqs, well
// under the round-0 request-rate wall of 4.2M scalar reqs).
// h_{t-1} staged per block into LDS via coherent global_load_dwordx4
// (sc0 sc1 = bypass L1/per-XCD L2, read the coherence point). k-ownership
// per lane: k = c*256 + lane*4 + e (contiguous ds_read_b128, conflict-free).
// Barrier: per-block slot stores (64B-strided, parallel at LLC, no RMW
// serialization) + wave-0 gather poll (__all over min of 4 slots/lane).
// Ordering (verified protocol): h-store (sc-relaxed AGENT) -> __syncthreads
// drains vmcnt(0) per wave -> tid0 slot store issued only after ALL waves'
// h-stores are at the coherence point -> slot=t+1 implies data visible.
// y-store moved AFTER the slot store: block-private output, its HBM
// write-ack completes during the poll window instead of sitting in the
// pre-barrier drain. NO threadfence / NO acquire (round-1 lesson: wbl2/inv
// storm). Ping-pong h buffers make WAR safe (see per-line comments).
__global__ __launch_bounds__(256, 1) void gru_kernel(
    const float* __restrict__ xi,    // (B,S,3H)
    const float* __restrict__ Whh,   // (3H,H)
    const float* __restrict__ bhh,   // (3H)
    const float* __restrict__ resid, // nullptr or (B,S,H)
    float* __restrict__ y,           // (B,S,H)
    float* __restrict__ hbuf,        // 2*4096 floats, zero-initialized
    unsigned* __restrict__ slots)    // GRU_BLOCKS slots, 16-u32 stride, zeroed
{
  const int tid = threadIdx.x;
  const int wave = tid >> 6, lane = tid & 63;
  const int j = (blockIdx.x << 2) + wave;  // 0..1023

  __shared__ float h_lds[4 * 1024];  // 16KB: h_{t-1} for all 4 batches

  // weights: w[g][c][e] = Whh[g*1024+j][c*256 + lane*4 + e]  (coalesced f4)
  float w[3][4][4];
#pragma unroll
  for (int g = 0; g < 3; ++g) {
    const float* row = Whh + (size_t)(g * 1024 + j) * 1024;
#pragma unroll
    for (int c = 0; c < 4; ++c) {
      F4 q; q.v = *(const float4*)(row + (c << 8) + (lane << 2));
#pragma unroll
      for (int e = 0; e < 4; ++e) w[g][c][e] = q.f[e];
    }
  }
  const float bh0 = bhh[j], bh1 = bhh[1024 + j], bh2 = bhh[2048 + j];

  // h_prev at this wave's own j: register-resident, identical in all lanes.
  float hold[B_SZ] = {0.0f, 0.0f, 0.0f, 0.0f};

  // xi prologue (t = 0); cached loads, wave-uniform address (broadcast)
  float xr[B_SZ], xz[B_SZ], xn[B_SZ];
#pragma unroll
  for (int b = 0; b < B_SZ; ++b) {
    const float* xp = xi + ((size_t)(b * S_LEN)) * 3072 + j;
    xr[b] = xp[0]; xz[b] = xp[1024]; xn[b] = xp[2048];
  }

  for (int t = 0; t < S_LEN; ++t) {
    float* hr_ = hbuf + ((t & 1) << 12);
    float* hw_ = hbuf + (((t + 1) & 1) << 12);

    // Stage h_{t-1} (4 x 1024 floats) into LDS: each of 256 threads loads
    // 4 coherent dwordx4 (sc0 sc1). Per-instruction, a wave covers 1KB
    // contiguous (lane-consecutive 16B) -- fully coalesced.
    {
      float4 r0, r1, r2, r3;
      const float* p0 = hr_ + (tid << 2);
      const float* p1 = p0 + 1024;
      const float* p2 = p0 + 2048;
      const float* p3 = p0 + 3072;
      asm volatile("global_load_dwordx4 %0, %1, off sc0 sc1" : "=v"(r0) : "v"(p0));
      asm volatile("global_load_dwordx4 %0, %1, off sc0 sc1" : "=v"(r1) : "v"(p1));
      asm volatile("global_load_dwordx4 %0, %1, off sc0 sc1" : "=v"(r2) : "v"(p2));
      asm volatile("global_load_dwordx4 %0, %1, off sc0 sc1" : "=v"(r3) : "v"(p3));
      asm volatile("s_waitcnt vmcnt(0)" ::: "memory");
      __builtin_amdgcn_sched_barrier(0);
      ((float4*)h_lds)[tid]       = r0;
      ((float4*)h_lds)[tid + 256] = r1;
      ((float4*)h_lds)[tid + 512] = r2;
      ((float4*)h_lds)[tid + 768] = r3;
    }
    __syncthreads();

    // Issue next step's xi loads now; latency hides under compute + barrier.
    float nxr[B_SZ], nxz[B_SZ], nxn[B_SZ];
    {
      const int tn = (t + 1 < S_LEN) ? (t + 1) : (S_LEN - 1);
#pragma unroll
      for (int b = 0; b < B_SZ; ++b) {
        const float* xp = xi + ((size_t)(b * S_LEN + tn)) * 3072 + j;
        nxr[b] = xp[0]; nxz[b] = xp[1024]; nxn[b] = xp[2048];
      }
    }

    // LDS -> regs: h[b][c][e] = h_lds[b*1024 + c*256 + lane*4 + e]
    float h[B_SZ][4][4];
#pragma unroll
    for (int b = 0; b < B_SZ; ++b)
#pragma unroll
      for (int c = 0; c < 4; ++c) {
        F4 q; q.v = *((const float4*)(h_lds + (b << 10) + (c << 8)) + lane);
#pragma unroll
        for (int e = 0; e < 4; ++e) h[b][c][e] = q.f[e];
      }

    // partial dots over this lane's 16 k's
    float a0[B_SZ], a1[B_SZ], a2[B_SZ];
#pragma unroll
    for (int b = 0; b < B_SZ; ++b) {
      float s0 = 0.f, s1 = 0.f, s2 = 0.f;
#pragma unroll
      for (int c = 0; c < 4; ++c)
#pragma unroll
        for (int e = 0; e < 4; ++e) {
          s0 += w[0][c][e] * h[b][c][e];
          s1 += w[1][c][e] * h[b][c][e];
          s2 += w[2][c][e] * h[b][c][e];
        }
      a0[b] = s0; a1[b] = s1; a2[b] = s2;
    }
    // butterfly reduce across 64 lanes (result in every lane)
#pragma unroll
    for (int m = 1; m < 64; m <<= 1)
#pragma unroll
      for (int b = 0; b < B_SZ; ++b) {
        a0[b] += __shfl_xor(a0[b], m, 64);
        a1[b] += __shfl_xor(a1[b], m, 64);
        a2[b] += __shfl_xor(a2[b], m, 64);
      }

    // gates (redundant in all lanes)
    float hnew[B_SZ];
#pragma unroll
    for (int b = 0; b < B_SZ; ++b) {
      const float r = sigmoid_f(xr[b] + a0[b] + bh0);
      const float z = sigmoid_f(xz[b] + a1[b] + bh1);
      const float n = tanhf(xn[b] + r * (a2[b] + bh2));
      hnew[b] = (1.0f - z) * n + z * hold[b];
      hold[b] = hnew[b];
    }

    // lane b (0..3) stores batch b's value for this j
    float sv = hnew[0];
    sv = (lane == 1) ? hnew[1] : sv;
    sv = (lane == 2) ? hnew[2] : sv;
    sv = (lane == 3) ? hnew[3] : sv;
    if (lane < B_SZ) {
      __hip_atomic_store(hw_ + (lane << 10) + j, sv,
                         __ATOMIC_RELAXED, __HIP_MEMORY_SCOPE_AGENT);
    }

    // ---- device-wide barrier: slot stores + gather poll ----
    __syncthreads();  // drains vmcnt(0): all waves' sc1 h-stores complete
    if (tid == 0)
      __hip_atomic_store(slots + (blockIdx.x << 4), (unsigned)(t + 1),
                         __ATOMIC_RELAXED, __HIP_MEMORY_SCOPE_AGENT);
    // y-store AFTER the slot store: block-private, ack overlaps the poll.
    if (lane < B_SZ) {
      const size_t oidx = ((size_t)(lane * S_LEN + t)) * 1024 + j;
      y[oidx] = resid ? (sv + resid[oidx]) : sv;
    }
    if (wave == 0) {
      const unsigned target = (unsigned)(t + 1);
      for (;;) {
        const unsigned v0 = __hip_atomic_load(slots + ((lane      ) << 4),
                             __ATOMIC_RELAXED, __HIP_MEMORY_SCOPE_AGENT);
        const unsigned v1 = __hip_atomic_load(slots + ((lane +  64) << 4),
                             __ATOMIC_RELAXED, __HIP_MEMORY_SCOPE_AGENT);
        const unsigned v2 = __hip_atomic_load(slots + ((lane + 128) << 4),
                             __ATOMIC_RELAXED, __HIP_MEMORY_SCOPE_AGENT);
        const unsigned v3 = __hip_atomic_load(slots + ((lane + 192) << 4),
                             __ATOMIC_RELAXED, __HIP_MEMORY_SCOPE_AGENT);
        unsigned m01 = v0 < v1 ? v0 : v1;
        unsigned m23 = v2 < v3 ? v2 : v3;
        unsigned m = m01 < m23 ? m01 : m23;
        if (__all(m >= target)) break;
        __builtin_amdgcn_s_sleep(1);
      }
    }
    __syncthreads();

    // rotate xi double-buffer
#pragma unroll
    for (int b = 0; b < B_SZ; ++b) {
      xr[b] = nxr[b]; xz[b] = nxz[b]; xn[b] = nxn[b];
    }
  }
}

// ---------------- column mean over S (gc = mean_t h2[b,t,:]) ----------------
__global__ __launch_bounds__(256) void colmean_kernel(
    const float* __restrict__ in, float* __restrict__ gc) {
  const int b = blockIdx.x >> 3, tc = blockIdx.x & 7;
  const int d = threadIdx.x;
  float s0 = 0.f, s1 = 0.f, s2 = 0.f, s3 = 0.f;
  const float* base = in + ((size_t)b * S_LEN + tc * 256) * D_DIM;
  for (int t = 0; t < 256; ++t) {
    const float* r = base + (size_t)t * D_DIM;
    s0 += r[d]; s1 += r[d + 256]; s2 += r[d + 512]; s3 += r[d + 768];
  }
  const float sc = 1.0f / (float)S_LEN;
  atomicAdd(&gc[b * D_DIM + d], s0 * sc);
  atomicAdd(&gc[b * D_DIM + d + 256], s1 * sc);
  atomicAdd(&gc[b * D_DIM + d + 512], s2 * sc);
  atomicAdd(&gc[b * D_DIM + d + 768], s3 * sc);
}

// ---------------- global MLP: gc(b,1024)->512->256->1, sigmoid ----------------
__global__ __launch_bounds__(256) void gmlp_kernel(
    const float* __restrict__ gc,
    const float* __restrict__ gw1, const float* __restrict__ gb1,
    const float* __restrict__ gw2, const float* __restrict__ gb2,
    const float* __restrict__ gw3, const float* __restrict__ gb3,
    float* __restrict__ gout) {
  const int b = blockIdx.x, tid = threadIdx.x;
  __shared__ float xin[1024];
  __shared__ float h1[512];
  __shared__ float h2[256];
#pragma unroll
  for (int i = 0; i < 4; ++i) xin[tid + i * 256] = gc[b * 1024 + tid + i * 256];
  __syncthreads();
  for (int o = tid; o < 512; o += 256) {
    const float* wr = gw1 + (size_t)o * 1024;
    float acc = gb1[o];
    for (int k = 0; k < 1024; k += 4) {
      const float4 wv = *(const float4*)(wr + k);
      acc += wv.x * xin[k] + wv.y * xin[k + 1] + wv.z * xin[k + 2] + wv.w * xin[k + 3];
    }
    h1[o] = gelu_f(acc);
  }
  __syncthreads();
  {
    const float* wr = gw2 + (size_t)tid * 512;
    float acc = gb2[tid];
    for (int k = 0; k < 512; k += 4) {
      const float4 wv = *(const float4*)(wr + k);
      acc += wv.x * h1[k] + wv.y * h1[k + 1] + wv.z * h1[k + 2] + wv.w * h1[k + 3];
    }
    h2[tid] = gelu_f(acc);
  }
  __syncthreads();
  float p = h2[tid] * gw3[tid];
#pragma unroll
  for (int m = 1; m < 64; m <<= 1) p += __shfl_xor(p, m, 64);
  __shared__ float rr[4];
  if ((tid & 63) == 0) rr[tid >> 6] = p;
  __syncthreads();
  if (tid == 0) gout[b] = sigmoid_f(rr[0] + rr[1] + rr[2] + rr[3] + gb3[0]);
}

// ---------------- coupling MLP final layer: (8192,256)@(256,) -> sigmoid ----------------
__global__ __launch_bounds__(256) void gemv_sig_kernel(
    const float* __restrict__ A, const float* __restrict__ w,
    const float* __restrict__ bias, float* __restrict__ out) {
  const int row = blockIdx.x * 4 + (threadIdx.x >> 6);
  const int lane = threadIdx.x & 63;
  F4 a, wv;
  a.v  = ((const float4*)(A + (size_t)row * 256))[lane];
  wv.v = ((const float4*)w)[lane];
  float p = a.f[0] * wv.f[0] + a.f[1] * wv.f[1] + a.f[2] * wv.f[2] + a.f[3] * wv.f[3];
#pragma unroll
  for (int m = 1; m < 64; m <<= 1) p += __shfl_xor(p, m, 64);
  if (lane == 0) out[row] = sigmoid_f(p + bias[0]);
}

// ---------------- mobius coupling update (in place, conjugate pairs) ----------------
// quarters [a,b,c,d] -> out += coup*[c,-d,-a,b]; pair (d, d+512), sign flips at d=256.
__global__ __launch_bounds__(256) void mobius_kernel(
    float* __restrict__ out, const float* __restrict__ tf,
    const float* __restrict__ g, const float* __restrict__ ar,
    const float* __restrict__ res) {
  const int idx = blockIdx.x * 256 + threadIdx.x;   // over 8192*512
  const int row = idx >> 9;
  const int d = idx & 511;
  const int b = row >> 11;
  const float combined = 0.7f * g[b] + 0.3f * tf[row];
  const float coup = 0.1f + ar[0] * (combined - 0.5f) * 2.0f;
  float* base = out + (size_t)row * 1024;
  const float f = base[d], s2 = base[d + 512];
  const float sgn = (d < 256) ? 1.0f : -1.0f;
  float nf = f + sgn * coup * s2;
  float ns = s2 - sgn * coup * f;
  if (res) {
    const float* rb = res + (size_t)row * 1024;
    nf += rb[d];
    ns += rb[d + 512];
  }
  base[d] = nf;
  base[d + 512] = ns;
}

extern "C" void kernel_launch(void* const* d_in, const int* in_sizes, int n_in,
                              void* d_out, int out_size, void* d_ws, size_t ws_size,
                              hipStream_t stream) {
  (void)in_sizes; (void)n_in; (void)out_size; (void)ws_size;
  const float* x    = (const float*)d_in[0];
  const float* g1w  = (const float*)d_in[1];
  const float* g1b  = (const float*)d_in[2];
  const float* g2w  = (const float*)d_in[3];
  const float* g2b  = (const float*)d_in[4];
  const float* Wih0 = (const float*)d_in[5];
  const float* Whh0 = (const float*)d_in[6];
  const float* bih0 = (const float*)d_in[7];
  const float* bhh0 = (const float*)d_in[8];
  const float* Wih1 = (const float*)d_in[9];
  const float* Whh1 = (const float*)d_in[10];
  const float* bih1 = (const float*)d_in[11];
  const float* bhh1 = (const float*)d_in[12];
  const float* cw1 = (const float*)d_in[13]; const float* cb1 = (const float*)d_in[14];
  const float* cw2 = (const float*)d_in[15]; const float* cb2 = (const float*)d_in[16];
  const float* cw3 = (const float*)d_in[17]; const float* cb3 = (const float*)d_in[18];
  const float* cw4 = (const float*)d_in[19]; const float* cb4 = (const float*)d_in[20];
  const float* gw1 = (const float*)d_in[21]; const float* gb1 = (const float*)d_in[22];
  const float* gw2 = (const float*)d_in[23]; const float* gb2 = (const float*)d_in[24];
  const float* gw3 = (const float*)d_in[25]; const float* gb3 = (const float*)d_in[26];
  const float* ar  = (const float*)d_in[27];
  const float* fw1 = (const float*)d_in[28]; const float* fb1 = (const float*)d_in[29];
  const float* fw2 = (const float*)d_in[30]; const float* fb2 = (const float*)d_in[31];
  float* outp = (float*)d_out;

  // workspace layout (floats): A 25165824 | Bb 8388608 | small ~36936
  float* A  = (float*)d_ws;
  float* Bb = A + 25165824;
  float* small = Bb + 8388608;
  float* gc   = small;                 // 4096
  float* gbuf = small + 4096;          // 8
  float* tf   = small + 4104;          // 8192
  float* hb0  = small + 12296;         // 8192 (2x4096 ping-pong)
  float* hb1  = small + 20488;         // 8192
  unsigned* slots0 = (unsigned*)(small + 28680);  // 256 slots x 16 u32 stride
  unsigned* slots1 = (unsigned*)(small + 32776);  // 256 slots x 16 u32 stride
  hipMemsetAsync(small, 0, (size_t)(36872 + 64) * sizeof(float), stream);

  // Block 1: LN -> GRU0 -> GRU1 (+x residual fused into GRU1 store)
  ln_kernel<<<8192, 256, 0, stream>>>(x, g1w, g1b, Bb);
  gemm_kernel<<<dim3(24, 64), 256, 0, stream>>>(Bb, 1024, Wih0, 1024, bih0, nullptr,
                                                A, 8192, 3072, 1024, 0);
  gru_kernel<<<GRU_BLOCKS, 256, 0, stream>>>(A, Whh0, bhh0, nullptr, Bb, hb0, slots0);
  gemm_kernel<<<dim3(24, 64), 256, 0, stream>>>(Bb, 1024, Wih1, 1024, bih1, nullptr,
                                                A, 8192, 3072, 1024, 0);
  gru_kernel<<<GRU_BLOCKS, 256, 0, stream>>>(A, Whh1, bhh1, x, outp, hb1, slots1);

  // Block 2: LN -> adaptive mobius (3 cycles) ; x2 lives in outp
  ln_kernel<<<8192, 256, 0, stream>>>(outp, g2w, g2b, Bb);
  colmean_kernel<<<32, 256, 0, stream>>>(Bb, gc);
  gmlp_kernel<<<4, 256, 0, stream>>>(gc, gw1, gb1, gw2, gb2, gw3, gb3, gbuf);
  float* c1o = A;              // 8192x1024
  float* c2o = A + 12582912;   // 8192x512
  float* c3o = A + 20971520;   // 8192x256
  for (int cyc = 0; cyc < 3; ++cyc) {
    gemm_kernel<<<dim3(8, 64), 256, 0, stream>>>(Bb, 1024, cw1, 1024, cb1, nullptr,
                                                 c1o, 8192, 1024, 1024, 1);
    gemm_kernel<<<dim3(4, 64), 256, 0, stream>>>(c1o, 1024, cw2, 1024, cb2, nullptr,
                                                 c2o, 8192, 512, 1024, 1);
    gemm_kernel<<<dim3(2, 64), 256, 0, stream>>>(c2o, 512, cw3, 512, cb3, nullptr,
                                                 c3o, 8192, 256, 512, 1);
    gemv_sig_kernel<<<2048, 256, 0, stream>>>(c3o, cw4, cb4, tf);
    // final cycle fuses x3 = x2 + out
    mobius_kernel<<<16384, 256, 0, stream>>>(Bb, tf, gbuf, ar,
                                             (cyc == 2) ? outp : nullptr);
  }

  // Block 3: FFN residual, K chunked in 2 so hidden fits the A region
  for (int c = 0; c < 2; ++c) {
    gemm_kernel<<<dim3(16, 64), 256, 0, stream>>>(Bb, 1024,
        fw1 + (size_t)c * 2048 * 1024, 1024, fb1 + c * 2048, nullptr,
        A, 8192, 2048, 1024, 1);
    gemm_kernel<<<dim3(8, 64), 256, 0, stream>>>(A, 2048,
        fw2 + c * 2048, 4096, (c == 0) ? fb2 : nullptr,
        (c == 0) ? Bb : outp,
        outp, 8192, 1024, 2048, 0);
  }
}